// Round 2
// baseline (3507.042 us; speedup 1.0000x reference)
//
#include <hip/hip_runtime.h>
#include <stdint.h>

typedef unsigned short u16;
typedef __bf16 bf16x8 __attribute__((ext_vector_type(8)));
typedef float f32x4 __attribute__((ext_vector_type(4)));

#define LOG2E 1.4426950408889634f

__device__ __forceinline__ float b2f(u16 b) {
    return __builtin_bit_cast(float, ((unsigned)b) << 16);
}
__device__ __forceinline__ u16 f2b(float f) {
    unsigned u = __builtin_bit_cast(unsigned, f);
    return (u16)((u + 0x7fffu + ((u >> 16) & 1u)) >> 16);
}
__device__ __forceinline__ void async16(const void* g, void* l) {
    __builtin_amdgcn_global_load_lds((const __attribute__((address_space(1))) void*)g,
                                     (__attribute__((address_space(3))) void*)l, 16, 0, 0);
}

// ---------------------------------------------------------------- add pe (f32 in)
__global__ __launch_bounds__(256) void add_pe_kernel(const float* __restrict__ x,
                                                     const float* __restrict__ pe,
                                                     float* __restrict__ hf,
                                                     u16* __restrict__ hb) {
    const size_t i = ((size_t)blockIdx.x * 256 + threadIdx.x) * 4;
    float4 xv = *(const float4*)(x + i);
    float4 pv = *(const float4*)(pe + (i & 2097151));  // i mod L*D (2^21)
    float4 f;
    f.x = xv.x + pv.x; f.y = xv.y + pv.y; f.z = xv.z + pv.z; f.w = xv.w + pv.w;
    *(float4*)(hf + i) = f;
    ushort4 hv;
    hv.x = f2b(f.x); hv.y = f2b(f.y); hv.z = f2b(f.z); hv.w = f2b(f.w);
    *(ushort4*)(hb + i) = hv;
}

// ------------------------------------------- transpose+cast: src f32 [K, srcStride] -> dst bf16 [N, K]
__global__ __launch_bounds__(256) void transpose_cast_kernel(const float* __restrict__ src,
                                                             u16* __restrict__ dst,
                                                             int srcStride, int K) {
    __shared__ __align__(16) u16 tile[64 * 72];
    const int n0 = blockIdx.x * 64, k0 = blockIdx.y * 64;
    const int t = threadIdx.x;
    const int r = t >> 3, c8 = (t & 7) * 8;
#pragma unroll
    for (int ph = 0; ph < 2; ph++) {
        const int rr = r + ph * 32;
        const float* s = src + (size_t)(k0 + rr) * srcStride + n0 + c8;
        float4 a = *(const float4*)s;
        float4 b = *(const float4*)(s + 4);
        u16* tr = tile + rr * 72 + c8;
        tr[0] = f2b(a.x); tr[1] = f2b(a.y); tr[2] = f2b(a.z); tr[3] = f2b(a.w);
        tr[4] = f2b(b.x); tr[5] = f2b(b.y); tr[6] = f2b(b.z); tr[7] = f2b(b.w);
    }
    __syncthreads();
#pragma unroll
    for (int ph = 0; ph < 2; ph++) {
        const int rr = r + ph * 32;
        union { float4 f; u16 u[8]; } ov;
#pragma unroll
        for (int j = 0; j < 8; j++) ov.u[j] = tile[(c8 + j) * 72 + rr];
        *(float4*)(dst + (size_t)(n0 + rr) * K + k0 + c8) = ov.f;
    }
}

// ---------------------------------------------------------------- GEMM C = A[M,K] * BT[N,K]^T
// MODE 0: QKV scatter (O0/O1/O2 = q,k,v bf16 [B,H,L,DH])
// MODE 1: bias + selu -> bf16 O0[M,N]
// MODE 2: bias -> f32 O0[M,N]
// MODE 3: accumulate f32: O0[M,N] += val
template <int MODE>
__global__ __launch_bounds__(256, 2) void gemm_kernel(const u16* __restrict__ A,
                                                      const u16* __restrict__ BT,
                                                      const float* __restrict__ bias,
                                                      void* __restrict__ O0, void* __restrict__ O1,
                                                      void* __restrict__ O2, int N, int K) {
    __shared__ __align__(16) u16 As[128 * 32];
    __shared__ __align__(16) u16 Bs[128 * 32];
    const int tid = threadIdx.x;
    const int lane = tid & 63, w = tid >> 6, quad = lane >> 4, l15 = lane & 15;
    const int m0 = blockIdx.y * 128, n0 = blockIdx.x * 128;
    const int wm = w >> 1, wn = w & 1;

    f32x4 acc[4][4] = {};

    const int srow = tid >> 2, scol = (tid & 3) * 8;
    const u16* Ag = A + (size_t)(m0 + srow) * K + scol;
    const u16* Bg = BT + (size_t)(n0 + srow) * K + scol;
    u16* Asd = As + tid * 8;
    u16* Bsd = Bs + tid * 8;
    const size_t half = (size_t)64 * K;

    for (int k0 = 0; k0 < K; k0 += 32) {
        __syncthreads();
        async16(Ag + k0, Asd);
        async16(Ag + k0 + half, Asd + 2048);
        async16(Bg + k0, Bsd);
        async16(Bg + k0 + half, Bsd + 2048);
        __syncthreads();
        bf16x8 af[4], bfr[4];
#pragma unroll
        for (int mt = 0; mt < 4; mt++)
            af[mt] = *(const bf16x8*)(As + (wm * 64 + mt * 16 + l15) * 32 + quad * 8);
#pragma unroll
        for (int nt = 0; nt < 4; nt++)
            bfr[nt] = *(const bf16x8*)(Bs + (wn * 64 + nt * 16 + l15) * 32 + quad * 8);
#pragma unroll
        for (int mt = 0; mt < 4; mt++)
#pragma unroll
            for (int nt = 0; nt < 4; nt++)
                acc[mt][nt] = __builtin_amdgcn_mfma_f32_16x16x32_bf16(af[mt], bfr[nt], acc[mt][nt], 0, 0, 0);
    }

#pragma unroll
    for (int nt = 0; nt < 4; nt++) {
        const int col = n0 + wn * 64 + nt * 16 + l15;
        float bv = 0.f;
        if (MODE == 1 || MODE == 2) bv = bias[col];
#pragma unroll
        for (int mt = 0; mt < 4; mt++) {
#pragma unroll
            for (int r = 0; r < 4; r++) {
                const int row = m0 + wm * 64 + mt * 16 + quad * 4 + r;
                float val = acc[mt][nt][r];
                if (MODE == 0) {
                    const int mat = col >> 10, cc = col & 1023;
                    const int head = cc >> 6, dh = cc & 63;
                    const int b = row >> 11, t = row & 2047;
                    u16* dst = (mat == 0) ? (u16*)O0 : (mat == 1) ? (u16*)O1 : (u16*)O2;
                    dst[(((size_t)(b * 16 + head)) * 2048 + t) * 64 + dh] = f2b(val);
                } else if (MODE == 1) {
                    val += bv;
                    const float s = 1.0507009873554805f, a = 1.6732632423543772f;
                    val = val > 0.f ? s * val : s * a * (__expf(val) - 1.f);
                    ((u16*)O0)[(size_t)row * N + col] = f2b(val);
                } else if (MODE == 2) {
                    ((float*)O0)[(size_t)row * N + col] = val + bv;
                } else {
                    ((float*)O0)[(size_t)row * N + col] += val;
                }
            }
        }
    }
}

// ---------------------------------------------------------------- flash attention (causal)
// q,k,v: bf16 [B*H, L, DH] ; o: bf16 [B, L, D]
__global__ __launch_bounds__(256) void attn_kernel(const u16* __restrict__ q,
                                                   const u16* __restrict__ k,
                                                   const u16* __restrict__ v,
                                                   u16* __restrict__ o) {
    __shared__ __align__(16) u16 Kt[64 * 72];
    __shared__ __align__(16) u16 Vt[64 * 72];      // transposed [d][kcol]
    __shared__ __align__(16) u16 Pt[4][32 * 72];   // per-wave P
    const int tid = threadIdx.x, lane = tid & 63, w = tid >> 6, quad = lane >> 4, l15 = lane & 15;
    const int bh = blockIdx.y, qt = blockIdx.x;
    const size_t base = (size_t)bh * 2048 * 64;
    const int q0 = qt * 128, wrow0 = q0 + w * 32;

    bf16x8 qf[2][2];
#pragma unroll
    for (int mt = 0; mt < 2; mt++)
#pragma unroll
        for (int ks = 0; ks < 2; ks++)
            qf[mt][ks] = *(const bf16x8*)(q + base + (size_t)(wrow0 + mt * 16 + l15) * 64 + ks * 32 + quad * 8);

    float m_[2][4], l_[2][4];
    f32x4 oacc[2][4] = {};
#pragma unroll
    for (int mt = 0; mt < 2; mt++)
#pragma unroll
        for (int r = 0; r < 4; r++) { m_[mt][r] = -1e30f; l_[mt][r] = 0.f; }

    const int ktmax = (qt + 1) * 2;
    const int srow = tid >> 3, sc8 = (tid & 7) * 8;

    for (int kt = 0; kt < ktmax; kt++) {
        __syncthreads();
#pragma unroll
        for (int ph = 0; ph < 2; ph++) {
            const int rr = srow + ph * 32;
            *(float4*)(Kt + rr * 72 + sc8) = *(const float4*)(k + base + (size_t)(kt * 64 + rr) * 64 + sc8);
            union { float4 f; u16 u[8]; } vv;
            vv.f = *(const float4*)(v + base + (size_t)(kt * 64 + rr) * 64 + sc8);
#pragma unroll
            for (int j = 0; j < 8; j++) Vt[(sc8 + j) * 72 + rr] = vv.u[j];
        }
        __syncthreads();
        const bool active = (kt * 64 <= wrow0 + 31);
        if (active) {
            f32x4 sc[2][4];
#pragma unroll
            for (int nt = 0; nt < 4; nt++) {
                bf16x8 kf0 = *(const bf16x8*)(Kt + (nt * 16 + l15) * 72 + quad * 8);
                bf16x8 kf1 = *(const bf16x8*)(Kt + (nt * 16 + l15) * 72 + 32 + quad * 8);
#pragma unroll
                for (int mt = 0; mt < 2; mt++) {
                    f32x4 z = {};
                    z = __builtin_amdgcn_mfma_f32_16x16x32_bf16(qf[mt][0], kf0, z, 0, 0, 0);
                    z = __builtin_amdgcn_mfma_f32_16x16x32_bf16(qf[mt][1], kf1, z, 0, 0, 0);
                    sc[mt][nt] = z;
                }
            }
            float alpha[2][4];
#pragma unroll
            for (int mt = 0; mt < 2; mt++) {
                const int rowb = wrow0 + mt * 16 + quad * 4;
#pragma unroll
                for (int r = 0; r < 4; r++) {
                    float sv[4];
                    float mx = -1e30f;
#pragma unroll
                    for (int nt = 0; nt < 4; nt++) {
                        const int colg = kt * 64 + nt * 16 + l15;
                        float s = sc[mt][nt][r] * 0.125f;
                        s = (colg <= rowb + r) ? s : -1e30f;
                        sv[nt] = s;
                        mx = fmaxf(mx, s);
                    }
#pragma unroll
                    for (int mm = 1; mm < 16; mm <<= 1) mx = fmaxf(mx, __shfl_xor(mx, mm, 64));
                    const float mnew = fmaxf(m_[mt][r], mx);
                    float rs = 0.f;
#pragma unroll
                    for (int nt = 0; nt < 4; nt++) {
                        const float p = exp2f((sv[nt] - mnew) * LOG2E);
                        rs += p;
                        Pt[w][(mt * 16 + quad * 4 + r) * 72 + nt * 16 + l15] = f2b(p);
                    }
#pragma unroll
                    for (int mm = 1; mm < 16; mm <<= 1) rs += __shfl_xor(rs, mm, 64);
                    const float al = exp2f((m_[mt][r] - mnew) * LOG2E);
                    l_[mt][r] = l_[mt][r] * al + rs;
                    m_[mt][r] = mnew;
                    alpha[mt][r] = al;
                }
            }
#pragma unroll
            for (int mt = 0; mt < 2; mt++)
#pragma unroll
                for (int nt = 0; nt < 4; nt++)
#pragma unroll
                    for (int r = 0; r < 4; r++) oacc[mt][nt][r] *= alpha[mt][r];
        }
        __syncthreads();
        if (active) {
            bf16x8 pf[2][2];
#pragma unroll
            for (int mt = 0; mt < 2; mt++)
#pragma unroll
                for (int ks = 0; ks < 2; ks++)
                    pf[mt][ks] = *(const bf16x8*)(Pt[w] + (mt * 16 + l15) * 72 + ks * 32 + quad * 8);
#pragma unroll
            for (int nt = 0; nt < 4; nt++) {
                bf16x8 vf0 = *(const bf16x8*)(Vt + (nt * 16 + l15) * 72 + quad * 8);
                bf16x8 vf1 = *(const bf16x8*)(Vt + (nt * 16 + l15) * 72 + 32 + quad * 8);
#pragma unroll
                for (int mt = 0; mt < 2; mt++) {
                    oacc[mt][nt] = __builtin_amdgcn_mfma_f32_16x16x32_bf16(pf[mt][0], vf0, oacc[mt][nt], 0, 0, 0);
                    oacc[mt][nt] = __builtin_amdgcn_mfma_f32_16x16x32_bf16(pf[mt][1], vf1, oacc[mt][nt], 0, 0, 0);
                }
            }
        }
    }

    const int b = bh >> 4, hh = bh & 15;
#pragma unroll
    for (int mt = 0; mt < 2; mt++)
#pragma unroll
        for (int nt = 0; nt < 4; nt++)
#pragma unroll
            for (int r = 0; r < 4; r++) {
                const int trow = wrow0 + mt * 16 + quad * 4 + r;
                const int col = hh * 64 + nt * 16 + l15;
                o[((size_t)b * 2048 + trow) * 1024 + col] = f2b(oacc[mt][nt][r] / l_[mt][r]);
            }
}

// ---------------------------------------------------------------- fused residual-add + layernorm
// ADD_BF16=1: add operand is bf16; else f32. g,b are f32.
template <int ADD_BF16>
__global__ __launch_bounds__(256) void ln_kernel(const float* __restrict__ hin,
                                                 const void* __restrict__ addp,
                                                 const float* __restrict__ g,
                                                 const float* __restrict__ bt,
                                                 float* __restrict__ hf_out,
                                                 u16* __restrict__ hb_out) {
    const int w = threadIdx.x >> 6, lane = threadIdx.x & 63;
    const size_t row = (size_t)blockIdx.x * 4 + w;
    const float4* hr = (const float4*)(hin + row * 1024);
    float4 xv[4];
    float s = 0.f, s2 = 0.f;
#pragma unroll
    for (int j = 0; j < 4; j++) {
        const int idx = lane + 64 * j;
        float4 a = hr[idx];
        float4 b;
        if (ADD_BF16) {
            ushort4 av = ((const ushort4*)addp)[row * 256 + idx];
            b.x = b2f(av.x); b.y = b2f(av.y); b.z = b2f(av.z); b.w = b2f(av.w);
        } else {
            b = ((const float4*)addp)[row * 256 + idx];
        }
        float4 x;
        x.x = a.x + b.x; x.y = a.y + b.y; x.z = a.z + b.z; x.w = a.w + b.w;
        xv[j] = x;
        s += x.x + x.y + x.z + x.w;
        s2 += x.x * x.x + x.y * x.y + x.z * x.z + x.w * x.w;
    }
#pragma unroll
    for (int mm = 1; mm < 64; mm <<= 1) { s += __shfl_xor(s, mm, 64); s2 += __shfl_xor(s2, mm, 64); }
    const float mean = s * (1.f / 1024.f);
    const float var = s2 * (1.f / 1024.f) - mean * mean;
    const float rstd = rsqrtf(var + 1e-5f);
    float4* of = (float4*)(hf_out + row * 1024);
    ushort4* ob = (ushort4*)(hb_out + row * 1024);
    const float4* gv = (const float4*)g;
    const float4* bv = (const float4*)bt;
#pragma unroll
    for (int j = 0; j < 4; j++) {
        const int idx = lane + 64 * j;
        float4 gg = gv[idx], bb = bv[idx];
        float4 x = xv[j], y;
        y.x = (x.x - mean) * rstd * gg.x + bb.x;
        y.y = (x.y - mean) * rstd * gg.y + bb.y;
        y.z = (x.z - mean) * rstd * gg.z + bb.z;
        y.w = (x.w - mean) * rstd * gg.w + bb.w;
        of[idx] = y;
        ushort4 oo;
        oo.x = f2b(y.x); oo.y = f2b(y.y); oo.z = f2b(y.z); oo.w = f2b(y.w);
        ob[idx] = oo;
    }
}

// ---------------------------------------------------------------- host
extern "C" void kernel_launch(void* const* d_in, const int* in_sizes, int n_in,
                              void* d_out, int out_size, void* d_ws, size_t ws_size,
                              hipStream_t stream) {
    const float* x   = (const float*)d_in[0];
    const float* pe  = (const float*)d_in[1];
    const float* wq  = (const float*)d_in[2];
    const float* wk  = (const float*)d_in[3];
    const float* wv  = (const float*)d_in[4];
    const float* l1g = (const float*)d_in[5];
    const float* l1b = (const float*)d_in[6];
    const float* w1  = (const float*)d_in[7];
    const float* b1  = (const float*)d_in[8];
    const float* w2  = (const float*)d_in[9];
    const float* b2  = (const float*)d_in[10];
    const float* l2g = (const float*)d_in[11];
    const float* l2b = (const float*)d_in[12];

    // 60 MB workspace layout (lifetime-aliased; stream order makes aliasing safe):
    char* ws = (char*)d_ws;
    float* hf   = (float*)(ws);                  // [ 0,16M)  f32 residual stream
    u16* hb     = (u16*)(ws + 16777216);         // [16,24M)  bf16 mirror of h
    u16* qb     = (u16*)(ws + 25165824);         // [24,32M)  Q bf16
    u16* kb     = (u16*)(ws + 33554432);         // [32,40M)  K bf16
    u16* vb     = (u16*)(ws + 41943040);         // [40,48M)  V bf16
    u16* wqkvT  = (u16*)(ws + 50331648);         // [48,54M)  qkv weightsT (dead after QKV gemm)
    u16* ob     = (u16*)(ws + 50331648);         // [48,56M)  attn out bf16 (aliases wqkvT)
    u16* wslot  = (u16*)(ws + 25165824);         // [24,28M)  per-half transposed FFN weight (aliases qb)
    u16* ub     = (u16*)(ws + 29360128);         // [28,44M)  ffn hidden half bf16 [4096,2048]
    float* mb   = (float*)(ws + 46137344);       // [44,60M)  ffn out f32 accumulator

    add_pe_kernel<<<4096, 256, 0, stream>>>(x, pe, hf, hb);

    for (int l = 0; l < 8; l++) {
        // --- QKV ---
        transpose_cast_kernel<<<dim3(16, 16), 256, 0, stream>>>(wq + (size_t)l * 1048576, wqkvT, 1024, 1024);
        transpose_cast_kernel<<<dim3(16, 16), 256, 0, stream>>>(wk + (size_t)l * 1048576, wqkvT + 1048576, 1024, 1024);
        transpose_cast_kernel<<<dim3(16, 16), 256, 0, stream>>>(wv + (size_t)l * 1048576, wqkvT + 2097152, 1024, 1024);
        gemm_kernel<0><<<dim3(24, 32), 256, 0, stream>>>(hb, wqkvT, nullptr, qb, kb, vb, 3072, 1024);
        // --- attention ---
        attn_kernel<<<dim3(16, 32), 256, 0, stream>>>(qb, kb, vb, ob);
        ln_kernel<1><<<1024, 256, 0, stream>>>(hf, ob, l1g + l * 1024, l1b + l * 1024, hf, hb);
        // --- FFN in two halves through one 4MB weight slot ---
        for (int half = 0; half < 2; half++) {
            // w1 column-slice [1024, 2048] -> wslot [2048, 1024]
            transpose_cast_kernel<<<dim3(32, 16), 256, 0, stream>>>(
                w1 + (size_t)l * 4194304 + half * 2048, wslot, 4096, 1024);
            gemm_kernel<1><<<dim3(16, 32), 256, 0, stream>>>(
                hb, wslot, b1 + l * 4096 + half * 2048, ub, nullptr, nullptr, 2048, 1024);
            // w2 row-slice [2048, 1024] -> wslot [1024, 2048]
            transpose_cast_kernel<<<dim3(16, 32), 256, 0, stream>>>(
                w2 + (size_t)l * 4194304 + (size_t)half * 2048 * 1024, wslot, 1024, 2048);
            if (half == 0)
                gemm_kernel<2><<<dim3(8, 32), 256, 0, stream>>>(
                    ub, wslot, b2 + l * 1024, mb, nullptr, nullptr, 1024, 2048);
            else
                gemm_kernel<3><<<dim3(8, 32), 256, 0, stream>>>(
                    ub, wslot, nullptr, mb, nullptr, nullptr, 1024, 2048);
        }
        const bool last = (l == 7);
        ln_kernel<0><<<1024, 256, 0, stream>>>(hf, mb, l2g + l * 1024, l2b + l * 1024,
                                               last ? (float*)d_out : hf, hb);
    }
}

// Round 3
// 3025.750 us; speedup vs baseline: 1.1591x; 1.1591x over previous
//
#include <hip/hip_runtime.h>
#include <stdint.h>

typedef unsigned short u16;
typedef __bf16 bf16x8 __attribute__((ext_vector_type(8)));
typedef float f32x4 __attribute__((ext_vector_type(4)));

__device__ __forceinline__ float b2f(u16 b) {
    return __builtin_bit_cast(float, ((unsigned)b) << 16);
}
__device__ __forceinline__ u16 f2b(float f) {
    unsigned u = __builtin_bit_cast(unsigned, f);
    return (u16)((u + 0x7fffu + ((u >> 16) & 1u)) >> 16);
}
__device__ __forceinline__ void async16(const void* g, void* l) {
    __builtin_amdgcn_global_load_lds((const __attribute__((address_space(1))) void*)g,
                                     (__attribute__((address_space(3))) void*)l, 16, 0, 0);
}

// ---------------------------------------------------------------- add pe (f32 in)
__global__ __launch_bounds__(256) void add_pe_kernel(const float* __restrict__ x,
                                                     const float* __restrict__ pe,
                                                     float* __restrict__ hf,
                                                     u16* __restrict__ hb) {
    const size_t i = ((size_t)blockIdx.x * 256 + threadIdx.x) * 4;
    float4 xv = *(const float4*)(x + i);
    float4 pv = *(const float4*)(pe + (i & 2097151));  // i mod L*D (2^21)
    float4 f;
    f.x = xv.x + pv.x; f.y = xv.y + pv.y; f.z = xv.z + pv.z; f.w = xv.w + pv.w;
    *(float4*)(hf + i) = f;
    ushort4 hv;
    hv.x = f2b(f.x); hv.y = f2b(f.y); hv.z = f2b(f.z); hv.w = f2b(f.w);
    *(ushort4*)(hb + i) = hv;
}

// ------------------------------------------- transpose+cast: src f32 [K, srcStride] -> dst bf16 [N, K]
__global__ __launch_bounds__(256) void transpose_cast_kernel(const float* __restrict__ src,
                                                             u16* __restrict__ dst,
                                                             int srcStride, int K) {
    __shared__ __align__(16) u16 tile[64 * 72];
    const int n0 = blockIdx.x * 64, k0 = blockIdx.y * 64;
    const int t = threadIdx.x;
    const int r = t >> 3, c8 = (t & 7) * 8;
#pragma unroll
    for (int ph = 0; ph < 2; ph++) {
        const int rr = r + ph * 32;
        const float* s = src + (size_t)(k0 + rr) * srcStride + n0 + c8;
        float4 a = *(const float4*)s;
        float4 b = *(const float4*)(s + 4);
        u16* tr = tile + rr * 72 + c8;
        tr[0] = f2b(a.x); tr[1] = f2b(a.y); tr[2] = f2b(a.z); tr[3] = f2b(a.w);
        tr[4] = f2b(b.x); tr[5] = f2b(b.y); tr[6] = f2b(b.z); tr[7] = f2b(b.w);
    }
    __syncthreads();
#pragma unroll
    for (int ph = 0; ph < 2; ph++) {
        const int rr = r + ph * 32;
        union { float4 f; u16 u[8]; } ov;
#pragma unroll
        for (int j = 0; j < 8; j++) ov.u[j] = tile[(c8 + j) * 72 + rr];
        *(float4*)(dst + (size_t)(n0 + rr) * K + k0 + c8) = ov.f;
    }
}

// ------------------------------------------- per-head V transpose: [bh][t][64] -> [bh][64][t] (bf16)
__global__ __launch_bounds__(256) void transpose_v_kernel(const u16* __restrict__ src,
                                                          u16* __restrict__ dst) {
    __shared__ __align__(16) u16 tile[64 * 72];
    const int bh = blockIdx.y, t0 = blockIdx.x * 64;
    const int t = threadIdx.x;
    const int r = t >> 3, c8 = (t & 7) * 8;
    const size_t base = (size_t)bh * 131072;
#pragma unroll
    for (int ph = 0; ph < 2; ph++) {
        const int rr = r + ph * 32;
        *(float4*)(tile + rr * 72 + c8) = *(const float4*)(src + base + (size_t)(t0 + rr) * 64 + c8);
    }
    __syncthreads();
#pragma unroll
    for (int ph = 0; ph < 2; ph++) {
        const int rr = r + ph * 32;  // d row
        union { float4 f; u16 u[8]; } ov;
#pragma unroll
        for (int j = 0; j < 8; j++) ov.u[j] = tile[(c8 + j) * 72 + rr];
        *(float4*)(dst + base + (size_t)rr * 2048 + t0 + c8) = ov.f;
    }
}

// ---------------------------------------------------------------- GEMM C = A[M,K] * BT[N,K]^T
// MTILES: 16-row m-tiles per wave (4 -> 128-row blocks, 2 -> 64-row blocks)
// MODE 0: QKV scatter (O0/O1/O2 = q,k,v bf16 [B,H,L,DH]); q pre-scaled by 0.125*log2(e)
// MODE 1: bias + selu -> bf16 O0[M,N]
// MODE 2: bias -> f32 O0[M,N]
// MODE 3: accumulate f32: O0[M,N] += val
template <int MODE, int MTILES>
__global__ __launch_bounds__(256, 2) void gemm_kernel(const u16* __restrict__ A,
                                                      const u16* __restrict__ BT,
                                                      const float* __restrict__ bias,
                                                      void* __restrict__ O0, void* __restrict__ O1,
                                                      void* __restrict__ O2, int N, int K) {
    __shared__ __align__(16) u16 As[MTILES * 32 * 32];
    __shared__ __align__(16) u16 Bs[128 * 32];
    const int tid = threadIdx.x;
    const int lane = tid & 63, w = tid >> 6, quad = lane >> 4, l15 = lane & 15;
    const int m0 = blockIdx.y * (MTILES * 32), n0 = blockIdx.x * 128;
    const int wm = w >> 1, wn = w & 1;

    f32x4 acc[MTILES][4] = {};

    const int srow = tid >> 2, scol = (tid & 3) * 8;
    const u16* Ag = A + (size_t)(m0 + srow) * K + scol;
    const u16* Bg = BT + (size_t)(n0 + srow) * K + scol;
    u16* Asd = As + tid * 8;
    u16* Bsd = Bs + tid * 8;
    const size_t half = (size_t)64 * K;

    for (int k0 = 0; k0 < K; k0 += 32) {
        __syncthreads();
#pragma unroll
        for (int i = 0; i < MTILES / 2; i++) async16(Ag + k0 + i * half, Asd + i * 2048);
        async16(Bg + k0, Bsd);
        async16(Bg + k0 + half, Bsd + 2048);
        __syncthreads();
        bf16x8 af[MTILES], bfr[4];
#pragma unroll
        for (int mt = 0; mt < MTILES; mt++)
            af[mt] = *(const bf16x8*)(As + (wm * (MTILES * 16) + mt * 16 + l15) * 32 + quad * 8);
#pragma unroll
        for (int nt = 0; nt < 4; nt++)
            bfr[nt] = *(const bf16x8*)(Bs + (wn * 64 + nt * 16 + l15) * 32 + quad * 8);
#pragma unroll
        for (int mt = 0; mt < MTILES; mt++)
#pragma unroll
            for (int nt = 0; nt < 4; nt++)
                acc[mt][nt] = __builtin_amdgcn_mfma_f32_16x16x32_bf16(af[mt], bfr[nt], acc[mt][nt], 0, 0, 0);
    }

#pragma unroll
    for (int nt = 0; nt < 4; nt++) {
        const int col = n0 + wn * 64 + nt * 16 + l15;
        float bv = 0.f;
        if (MODE == 1 || MODE == 2) bv = bias[col];
#pragma unroll
        for (int mt = 0; mt < MTILES; mt++) {
#pragma unroll
            for (int r = 0; r < 4; r++) {
                const int row = m0 + wm * (MTILES * 16) + mt * 16 + quad * 4 + r;
                float val = acc[mt][nt][r];
                if (MODE == 0) {
                    const int mat = col >> 10, cc = col & 1023;
                    const int head = cc >> 6, dh = cc & 63;
                    const int b = row >> 11, t = row & 2047;
                    if (mat == 0) val *= 0.18033688f;  // 0.125 * log2(e): base-2 softmax domain
                    u16* dst = (mat == 0) ? (u16*)O0 : (mat == 1) ? (u16*)O1 : (u16*)O2;
                    dst[(((size_t)(b * 16 + head)) * 2048 + t) * 64 + dh] = f2b(val);
                } else if (MODE == 1) {
                    val += bv;
                    const float s = 1.0507009873554805f, a = 1.6732632423543772f;
                    val = val > 0.f ? s * val : s * a * (__expf(val) - 1.f);
                    ((u16*)O0)[(size_t)row * N + col] = f2b(val);
                } else if (MODE == 2) {
                    ((float*)O0)[(size_t)row * N + col] = val + bv;
                } else {
                    ((float*)O0)[(size_t)row * N + col] += val;
                }
            }
        }
    }
}

// ---------------------------------------------------------------- flash attention (causal)
// q (pre-scaled): bf16 [B*H, L, 64]; k: bf16 [B*H, L, 64]; vT: bf16 [B*H, 64, L]; o: bf16 [B,L,D]
__global__ __launch_bounds__(256) void attn_kernel(const u16* __restrict__ q,
                                                   const u16* __restrict__ k,
                                                   const u16* __restrict__ vT,
                                                   u16* __restrict__ o) {
    __shared__ __align__(16) u16 Kt[64 * 72];      // [k][d]
    __shared__ __align__(16) u16 Vt[64 * 72];      // [d][k]
    __shared__ __align__(16) u16 Pt[4][32 * 72];   // per-wave P
    const int tid = threadIdx.x, lane = tid & 63, w = tid >> 6, quad = lane >> 4, l15 = lane & 15;
    const int bh = blockIdx.x;
    const int qt = 15 - blockIdx.y;                // LPT: heavy diagonal blocks dispatch first
    const size_t base = (size_t)bh * 131072;
    const int q0 = qt * 128, wrow0 = q0 + w * 32;

    bf16x8 qf[2][2];
#pragma unroll
    for (int mt = 0; mt < 2; mt++)
#pragma unroll
        for (int ks = 0; ks < 2; ks++)
            qf[mt][ks] = *(const bf16x8*)(q + base + (size_t)(wrow0 + mt * 16 + l15) * 64 + ks * 32 + quad * 8);

    float m_[2][4], l_[2][4];
    f32x4 oacc[2][4] = {};
#pragma unroll
    for (int mt = 0; mt < 2; mt++)
#pragma unroll
        for (int r = 0; r < 4; r++) { m_[mt][r] = -1e30f; l_[mt][r] = 0.f; }

    const int ktmax = (qt + 1) * 2;
    const int srow = tid >> 3, sc8 = (tid & 7) * 8;

    for (int kt = 0; kt < ktmax; kt++) {
        __syncthreads();
#pragma unroll
        for (int ph = 0; ph < 2; ph++) {
            const int rr = srow + ph * 32;
            *(float4*)(Kt + rr * 72 + sc8) = *(const float4*)(k + base + (size_t)(kt * 64 + rr) * 64 + sc8);
            *(float4*)(Vt + rr * 72 + sc8) = *(const float4*)(vT + base + (size_t)rr * 2048 + kt * 64 + sc8);
        }
        __syncthreads();
        const bool active = (kt * 64 <= wrow0 + 31);
        if (active) {
            f32x4 sc[2][4];
#pragma unroll
            for (int nt = 0; nt < 4; nt++) {
                bf16x8 kf0 = *(const bf16x8*)(Kt + (nt * 16 + l15) * 72 + quad * 8);
                bf16x8 kf1 = *(const bf16x8*)(Kt + (nt * 16 + l15) * 72 + 32 + quad * 8);
#pragma unroll
                for (int mt = 0; mt < 2; mt++) {
                    f32x4 z = {};
                    z = __builtin_amdgcn_mfma_f32_16x16x32_bf16(qf[mt][0], kf0, z, 0, 0, 0);
                    z = __builtin_amdgcn_mfma_f32_16x16x32_bf16(qf[mt][1], kf1, z, 0, 0, 0);
                    sc[mt][nt] = z;
                }
            }
            float alpha[2][4];
#pragma unroll
            for (int mt = 0; mt < 2; mt++) {
                const int rowb = wrow0 + mt * 16 + quad * 4;
#pragma unroll
                for (int r = 0; r < 4; r++) {
                    float sv[4];
                    float mx = -1e30f;
#pragma unroll
                    for (int nt = 0; nt < 4; nt++) {
                        const int colg = kt * 64 + nt * 16 + l15;
                        float s = sc[mt][nt][r];            // already in base-2 domain
                        s = (colg <= rowb + r) ? s : -1e30f;
                        sv[nt] = s;
                        mx = fmaxf(mx, s);
                    }
#pragma unroll
                    for (int mm = 1; mm < 16; mm <<= 1) mx = fmaxf(mx, __shfl_xor(mx, mm, 64));
                    const float mnew = fmaxf(m_[mt][r], mx);
                    float rs = 0.f;
#pragma unroll
                    for (int nt = 0; nt < 4; nt++) {
                        const float p = exp2f(sv[nt] - mnew);
                        rs += p;
                        Pt[w][(mt * 16 + quad * 4 + r) * 72 + nt * 16 + l15] = f2b(p);
                    }
#pragma unroll
                    for (int mm = 1; mm < 16; mm <<= 1) rs += __shfl_xor(rs, mm, 64);
                    const float al = exp2f(m_[mt][r] - mnew);
                    l_[mt][r] = l_[mt][r] * al + rs;
                    m_[mt][r] = mnew;
                    alpha[mt][r] = al;
                }
            }
#pragma unroll
            for (int mt = 0; mt < 2; mt++)
#pragma unroll
                for (int nt = 0; nt < 4; nt++)
#pragma unroll
                    for (int r = 0; r < 4; r++) oacc[mt][nt][r] *= alpha[mt][r];

            bf16x8 pf[2][2];
#pragma unroll
            for (int mt = 0; mt < 2; mt++)
#pragma unroll
                for (int ks = 0; ks < 2; ks++)
                    pf[mt][ks] = *(const bf16x8*)(Pt[w] + (mt * 16 + l15) * 72 + ks * 32 + quad * 8);
#pragma unroll
            for (int nt = 0; nt < 4; nt++) {
                bf16x8 vf0 = *(const bf16x8*)(Vt + (nt * 16 + l15) * 72 + quad * 8);
                bf16x8 vf1 = *(const bf16x8*)(Vt + (nt * 16 + l15) * 72 + 32 + quad * 8);
#pragma unroll
                for (int mt = 0; mt < 2; mt++) {
                    oacc[mt][nt] = __builtin_amdgcn_mfma_f32_16x16x32_bf16(pf[mt][0], vf0, oacc[mt][nt], 0, 0, 0);
                    oacc[mt][nt] = __builtin_amdgcn_mfma_f32_16x16x32_bf16(pf[mt][1], vf1, oacc[mt][nt], 0, 0, 0);
                }
            }
        }
    }

    const int b = bh >> 4, hh = bh & 15;
#pragma unroll
    for (int mt = 0; mt < 2; mt++)
#pragma unroll
        for (int nt = 0; nt < 4; nt++)
#pragma unroll
            for (int r = 0; r < 4; r++) {
                const int trow = wrow0 + mt * 16 + quad * 4 + r;
                const int col = hh * 64 + nt * 16 + l15;
                o[((size_t)b * 2048 + trow) * 1024 + col] = f2b(oacc[mt][nt][r] / l_[mt][r]);
            }
}

// ---------------------------------------------------------------- fused residual-add + layernorm
// ADD_BF16=1: add operand is bf16; else f32. g,b are f32.
template <int ADD_BF16>
__global__ __launch_bounds__(256) void ln_kernel(const float* __restrict__ hin,
                                                 const void* __restrict__ addp,
                                                 const float* __restrict__ g,
                                                 const float* __restrict__ bt,
                                                 float* __restrict__ hf_out,
                                                 u16* __restrict__ hb_out) {
    const int w = threadIdx.x >> 6, lane = threadIdx.x & 63;
    const size_t row = (size_t)blockIdx.x * 4 + w;
    const float4* hr = (const float4*)(hin + row * 1024);
    float4 xv[4];
    float s = 0.f, s2 = 0.f;
#pragma unroll
    for (int j = 0; j < 4; j++) {
        const int idx = lane + 64 * j;
        float4 a = hr[idx];
        float4 b;
        if (ADD_BF16) {
            ushort4 av = ((const ushort4*)addp)[row * 256 + idx];
            b.x = b2f(av.x); b.y = b2f(av.y); b.z = b2f(av.z); b.w = b2f(av.w);
        } else {
            b = ((const float4*)addp)[row * 256 + idx];
        }
        float4 x;
        x.x = a.x + b.x; x.y = a.y + b.y; x.z = a.z + b.z; x.w = a.w + b.w;
        xv[j] = x;
        s += x.x + x.y + x.z + x.w;
        s2 += x.x * x.x + x.y * x.y + x.z * x.z + x.w * x.w;
    }
#pragma unroll
    for (int mm = 1; mm < 64; mm <<= 1) { s += __shfl_xor(s, mm, 64); s2 += __shfl_xor(s2, mm, 64); }
    const float mean = s * (1.f / 1024.f);
    const float var = s2 * (1.f / 1024.f) - mean * mean;
    const float rstd = rsqrtf(var + 1e-5f);
    float4* of = (float4*)(hf_out + row * 1024);
    ushort4* ob = (ushort4*)(hb_out + row * 1024);
    const float4* gv = (const float4*)g;
    const float4* bv = (const float4*)bt;
#pragma unroll
    for (int j = 0; j < 4; j++) {
        const int idx = lane + 64 * j;
        float4 gg = gv[idx], bb = bv[idx];
        float4 x = xv[j], y;
        y.x = (x.x - mean) * rstd * gg.x + bb.x;
        y.y = (x.y - mean) * rstd * gg.y + bb.y;
        y.z = (x.z - mean) * rstd * gg.z + bb.z;
        y.w = (x.w - mean) * rstd * gg.w + bb.w;
        of[idx] = y;
        ushort4 oo;
        oo.x = f2b(y.x); oo.y = f2b(y.y); oo.z = f2b(y.z); oo.w = f2b(y.w);
        ob[idx] = oo;
    }
}

// ---------------------------------------------------------------- host
extern "C" void kernel_launch(void* const* d_in, const int* in_sizes, int n_in,
                              void* d_out, int out_size, void* d_ws, size_t ws_size,
                              hipStream_t stream) {
    const float* x   = (const float*)d_in[0];
    const float* pe  = (const float*)d_in[1];
    const float* wq  = (const float*)d_in[2];
    const float* wk  = (const float*)d_in[3];
    const float* wv  = (const float*)d_in[4];
    const float* l1g = (const float*)d_in[5];
    const float* l1b = (const float*)d_in[6];
    const float* w1  = (const float*)d_in[7];
    const float* b1  = (const float*)d_in[8];
    const float* w2  = (const float*)d_in[9];
    const float* b2  = (const float*)d_in[10];
    const float* l2g = (const float*)d_in[11];
    const float* l2b = (const float*)d_in[12];

    // 60 MB workspace, lifetime-aliased (stream order makes aliasing safe):
    char* ws = (char*)d_ws;
    float* hf   = (float*)(ws);                  // [ 0,16M) f32 residual stream
    u16* hb     = (u16*)(ws + 16777216);         // [16,24M) bf16 mirror of h
    u16* qb     = (u16*)(ws + 25165824);         // [24,32M) Q bf16 (pre-scaled)
    u16* kb     = (u16*)(ws + 33554432);         // [32,40M) K bf16
    u16* vb     = (u16*)(ws + 41943040);         // [40,48M) V bf16 natural [bh][t][d]
    u16* wqkvT  = (u16*)(ws + 50331648);         // [48,54M) qkv weightsT (dead after QKV gemm)
    u16* vbt    = (u16*)(ws + 50331648);         // [48,56M) V^T [bh][d][t] (aliases wqkvT)
    u16* ob     = (u16*)(ws + 41943040);         // [40,48M) attn out bf16 (aliases vb; vb dead after transpose_v)
    u16* wslot  = (u16*)(ws + 25165824);         // [24,28M) FFN weight slot (aliases qb, dead after attn)
    u16* ub     = (u16*)(ws + 29360128);         // [28,44M) ffn hidden half bf16 [4096,2048]
    float* mb   = (float*)(ws + 46137344);       // [44,60M) ffn out f32 accumulator

    add_pe_kernel<<<4096, 256, 0, stream>>>(x, pe, hf, hb);

    for (int l = 0; l < 8; l++) {
        // --- QKV ---
        transpose_cast_kernel<<<dim3(16, 16), 256, 0, stream>>>(wq + (size_t)l * 1048576, wqkvT, 1024, 1024);
        transpose_cast_kernel<<<dim3(16, 16), 256, 0, stream>>>(wk + (size_t)l * 1048576, wqkvT + 1048576, 1024, 1024);
        transpose_cast_kernel<<<dim3(16, 16), 256, 0, stream>>>(wv + (size_t)l * 1048576, wqkvT + 2097152, 1024, 1024);
        gemm_kernel<0, 4><<<dim3(24, 32), 256, 0, stream>>>(hb, wqkvT, nullptr, qb, kb, vb, 3072, 1024);
        transpose_v_kernel<<<dim3(32, 32), 256, 0, stream>>>(vb, vbt);
        // --- attention ---
        attn_kernel<<<dim3(32, 16), 256, 0, stream>>>(qb, kb, vbt, ob);
        ln_kernel<1><<<1024, 256, 0, stream>>>(hf, ob, l1g + l * 1024, l1b + l * 1024, hf, hb);
        // --- FFN in two halves through one 4MB weight slot ---
        for (int half = 0; half < 2; half++) {
            transpose_cast_kernel<<<dim3(32, 16), 256, 0, stream>>>(
                w1 + (size_t)l * 4194304 + half * 2048, wslot, 4096, 1024);
            gemm_kernel<1, 4><<<dim3(16, 32), 256, 0, stream>>>(
                hb, wslot, b1 + l * 4096 + half * 2048, ub, nullptr, nullptr, 2048, 1024);
            transpose_cast_kernel<<<dim3(16, 32), 256, 0, stream>>>(
                w2 + (size_t)l * 4194304 + (size_t)half * 2048 * 1024, wslot, 1024, 2048);
            if (half == 0)
                gemm_kernel<2, 2><<<dim3(8, 64), 256, 0, stream>>>(
                    ub, wslot, b2 + l * 1024, mb, nullptr, nullptr, 1024, 2048);
            else
                gemm_kernel<3, 2><<<dim3(8, 64), 256, 0, stream>>>(
                    ub, wslot, nullptr, mb, nullptr, nullptr, 1024, 2048);
        }
        const bool last = (l == 7);
        ln_kernel<0><<<1024, 256, 0, stream>>>(hf, mb, l2g + l * 1024, l2b + l * 1024,
                                               last ? (float*)d_out : hf, hb);
    }
}

// Round 4
// 2510.304 us; speedup vs baseline: 1.3971x; 1.2053x over previous
//
#include <hip/hip_runtime.h>
#include <stdint.h>

typedef unsigned short u16;
typedef __bf16 bf16x8 __attribute__((ext_vector_type(8)));
typedef __bf16 bf16x4 __attribute__((ext_vector_type(4)));
typedef float f32x4 __attribute__((ext_vector_type(4)));

__device__ __forceinline__ float b2f(u16 b) {
    return __builtin_bit_cast(float, ((unsigned)b) << 16);
}
__device__ __forceinline__ u16 f2b(float f) {
    unsigned u = __builtin_bit_cast(unsigned, f);
    return (u16)((u + 0x7fffu + ((u >> 16) & 1u)) >> 16);
}
__device__ __forceinline__ void async16(const void* g, void* l) {
    __builtin_amdgcn_global_load_lds((const __attribute__((address_space(1))) void*)g,
                                     (__attribute__((address_space(3))) void*)l, 16, 0, 0);
}

// ---------------------------------------------------------------- add pe (f32 in)
__global__ __launch_bounds__(256) void add_pe_kernel(const float* __restrict__ x,
                                                     const float* __restrict__ pe,
                                                     float* __restrict__ hf,
                                                     u16* __restrict__ hb) {
    const size_t i = ((size_t)blockIdx.x * 256 + threadIdx.x) * 4;
    float4 xv = *(const float4*)(x + i);
    float4 pv = *(const float4*)(pe + (i & 2097151));  // i mod L*D (2^21)
    float4 f;
    f.x = xv.x + pv.x; f.y = xv.y + pv.y; f.z = xv.z + pv.z; f.w = xv.w + pv.w;
    *(float4*)(hf + i) = f;
    ushort4 hv;
    hv.x = f2b(f.x); hv.y = f2b(f.y); hv.z = f2b(f.z); hv.w = f2b(f.w);
    *(ushort4*)(hb + i) = hv;
}

// ------------------------------------------- transpose+cast: src f32 [K, srcStride] -> dst bf16 [N, K]
__global__ __launch_bounds__(256) void transpose_cast_kernel(const float* __restrict__ src,
                                                             u16* __restrict__ dst,
                                                             int srcStride, int K) {
    __shared__ __align__(16) u16 tile[64 * 72];
    const int n0 = blockIdx.x * 64, k0 = blockIdx.y * 64;
    const int t = threadIdx.x;
    const int r = t >> 3, c8 = (t & 7) * 8;
#pragma unroll
    for (int ph = 0; ph < 2; ph++) {
        const int rr = r + ph * 32;
        const float* s = src + (size_t)(k0 + rr) * srcStride + n0 + c8;
        float4 a = *(const float4*)s;
        float4 b = *(const float4*)(s + 4);
        u16* tr = tile + rr * 72 + c8;
        tr[0] = f2b(a.x); tr[1] = f2b(a.y); tr[2] = f2b(a.z); tr[3] = f2b(a.w);
        tr[4] = f2b(b.x); tr[5] = f2b(b.y); tr[6] = f2b(b.z); tr[7] = f2b(b.w);
    }
    __syncthreads();
#pragma unroll
    for (int ph = 0; ph < 2; ph++) {
        const int rr = r + ph * 32;
        union { float4 f; u16 u[8]; } ov;
#pragma unroll
        for (int j = 0; j < 8; j++) ov.u[j] = tile[(c8 + j) * 72 + rr];
        *(float4*)(dst + (size_t)(n0 + rr) * K + k0 + c8) = ov.f;
    }
}

// ------------------------------------------- fused QKV weight transpose: 3 x [1024,1024] f32 -> bf16^T
__global__ __launch_bounds__(256) void transpose_qkv_kernel(const float* __restrict__ wq,
                                                            const float* __restrict__ wk,
                                                            const float* __restrict__ wv,
                                                            u16* __restrict__ dst) {
    __shared__ __align__(16) u16 tile[64 * 72];
    const float* src = (blockIdx.z == 0) ? wq : (blockIdx.z == 1) ? wk : wv;
    u16* d = dst + (size_t)blockIdx.z * 1048576;
    const int n0 = blockIdx.x * 64, k0 = blockIdx.y * 64;
    const int t = threadIdx.x;
    const int r = t >> 3, c8 = (t & 7) * 8;
#pragma unroll
    for (int ph = 0; ph < 2; ph++) {
        const int rr = r + ph * 32;
        const float* s = src + (size_t)(k0 + rr) * 1024 + n0 + c8;
        float4 a = *(const float4*)s;
        float4 b = *(const float4*)(s + 4);
        u16* tr = tile + rr * 72 + c8;
        tr[0] = f2b(a.x); tr[1] = f2b(a.y); tr[2] = f2b(a.z); tr[3] = f2b(a.w);
        tr[4] = f2b(b.x); tr[5] = f2b(b.y); tr[6] = f2b(b.z); tr[7] = f2b(b.w);
    }
    __syncthreads();
#pragma unroll
    for (int ph = 0; ph < 2; ph++) {
        const int rr = r + ph * 32;
        union { float4 f; u16 u[8]; } ov;
#pragma unroll
        for (int j = 0; j < 8; j++) ov.u[j] = tile[(c8 + j) * 72 + rr];
        *(float4*)(d + (size_t)(n0 + rr) * 1024 + k0 + c8) = ov.f;
    }
}

// ------------------------------------------- per-head V transpose: [bh][t][64] -> [bh][64][t] (bf16)
__global__ __launch_bounds__(256) void transpose_v_kernel(const u16* __restrict__ src,
                                                          u16* __restrict__ dst) {
    __shared__ __align__(16) u16 tile[64 * 72];
    const int bh = blockIdx.y, t0 = blockIdx.x * 64;
    const int t = threadIdx.x;
    const int r = t >> 3, c8 = (t & 7) * 8;
    const size_t base = (size_t)bh * 131072;
#pragma unroll
    for (int ph = 0; ph < 2; ph++) {
        const int rr = r + ph * 32;
        *(float4*)(tile + rr * 72 + c8) = *(const float4*)(src + base + (size_t)(t0 + rr) * 64 + c8);
    }
    __syncthreads();
#pragma unroll
    for (int ph = 0; ph < 2; ph++) {
        const int rr = r + ph * 32;  // d row
        union { float4 f; u16 u[8]; } ov;
#pragma unroll
        for (int j = 0; j < 8; j++) ov.u[j] = tile[(c8 + j) * 72 + rr];
        *(float4*)(dst + base + (size_t)rr * 2048 + t0 + c8) = ov.f;
    }
}

// ---------------------------------------------------------------- GEMM C = A[M,K] * BT[N,K]^T
// MTILES: 16-row m-tiles per wave (4 -> 128-row blocks, 2 -> 64-row blocks)
// MODE 0: QKV scatter (O0/O1/O2 = q,k,v bf16 [B,H,L,DH]); q pre-scaled by 0.125*log2(e)
// MODE 1: bias + selu -> bf16 O0[M,N]
// MODE 2: bias -> f32 O0[M,N]
// MODE 3: accumulate f32: O0[M,N] += val
template <int MODE, int MTILES>
__global__ __launch_bounds__(256, 2) void gemm_kernel(const u16* __restrict__ A,
                                                      const u16* __restrict__ BT,
                                                      const float* __restrict__ bias,
                                                      void* __restrict__ O0, void* __restrict__ O1,
                                                      void* __restrict__ O2, int N, int K) {
    __shared__ __align__(16) u16 As[MTILES * 32 * 32];
    __shared__ __align__(16) u16 Bs[128 * 32];
    const int tid = threadIdx.x;
    const int lane = tid & 63, w = tid >> 6, quad = lane >> 4, l15 = lane & 15;
    const int m0 = blockIdx.y * (MTILES * 32), n0 = blockIdx.x * 128;
    const int wm = w >> 1, wn = w & 1;

    f32x4 acc[MTILES][4] = {};

    const int srow = tid >> 2, scol = (tid & 3) * 8;
    const u16* Ag = A + (size_t)(m0 + srow) * K + scol;
    const u16* Bg = BT + (size_t)(n0 + srow) * K + scol;
    u16* Asd = As + tid * 8;
    u16* Bsd = Bs + tid * 8;
    const size_t half = (size_t)64 * K;

    for (int k0 = 0; k0 < K; k0 += 32) {
        __syncthreads();
#pragma unroll
        for (int i = 0; i < MTILES / 2; i++) async16(Ag + k0 + i * half, Asd + i * 2048);
        async16(Bg + k0, Bsd);
        async16(Bg + k0 + half, Bsd + 2048);
        __syncthreads();
        bf16x8 af[MTILES], bfr[4];
#pragma unroll
        for (int mt = 0; mt < MTILES; mt++)
            af[mt] = *(const bf16x8*)(As + (wm * (MTILES * 16) + mt * 16 + l15) * 32 + quad * 8);
#pragma unroll
        for (int nt = 0; nt < 4; nt++)
            bfr[nt] = *(const bf16x8*)(Bs + (wn * 64 + nt * 16 + l15) * 32 + quad * 8);
#pragma unroll
        for (int mt = 0; mt < MTILES; mt++)
#pragma unroll
            for (int nt = 0; nt < 4; nt++)
                acc[mt][nt] = __builtin_amdgcn_mfma_f32_16x16x32_bf16(af[mt], bfr[nt], acc[mt][nt], 0, 0, 0);
    }

#pragma unroll
    for (int nt = 0; nt < 4; nt++) {
        const int col = n0 + wn * 64 + nt * 16 + l15;
        float bv = 0.f;
        if (MODE == 1 || MODE == 2) bv = bias[col];
#pragma unroll
        for (int mt = 0; mt < MTILES; mt++) {
#pragma unroll
            for (int r = 0; r < 4; r++) {
                const int row = m0 + wm * (MTILES * 16) + mt * 16 + quad * 4 + r;
                float val = acc[mt][nt][r];
                if (MODE == 0) {
                    const int mat = col >> 10, cc = col & 1023;
                    const int head = cc >> 6, dh = cc & 63;
                    const int b = row >> 11, t = row & 2047;
                    if (mat == 0) val *= 0.18033688f;  // 0.125 * log2(e): base-2 softmax domain
                    u16* dst = (mat == 0) ? (u16*)O0 : (mat == 1) ? (u16*)O1 : (u16*)O2;
                    dst[(((size_t)(b * 16 + head)) * 2048 + t) * 64 + dh] = f2b(val);
                } else if (MODE == 1) {
                    val += bv;
                    const float s = 1.0507009873554805f, a = 1.6732632423543772f;
                    val = val > 0.f ? s * val : s * a * (__expf(val) - 1.f);
                    ((u16*)O0)[(size_t)row * N + col] = f2b(val);
                } else if (MODE == 2) {
                    ((float*)O0)[(size_t)row * N + col] = val + bv;
                } else {
                    ((float*)O0)[(size_t)row * N + col] += val;
                }
            }
        }
    }
}

// ---------------------------------------------------------------- flash attention (causal), S^T form
// q (pre-scaled to base-2 domain): bf16 [B*H, L, 64]; k: bf16 [B*H, L, 64];
// vT: bf16 [B*H, 64, L]; o: bf16 [B, L, D]
// Scores computed TRANSPOSED (S^T = K·Q^T): k along C-rows, q along lanes, so the
// softmax k-reduction is in-register (+2 shfl), not 8 shfl rounds per row.
__global__ __launch_bounds__(256) void attn_kernel(const u16* __restrict__ q,
                                                   const u16* __restrict__ k,
                                                   const u16* __restrict__ vT,
                                                   u16* __restrict__ o) {
    __shared__ __align__(16) u16 Kt[64 * 72];      // [k][d]
    __shared__ __align__(16) u16 Vt[64 * 72];      // [d][k]
    __shared__ __align__(16) u16 Pt[4][32 * 72];   // per-wave P [q][k]
    const int tid = threadIdx.x, lane = tid & 63, w = tid >> 6, quad = lane >> 4, l15 = lane & 15;
    const int bh = blockIdx.x;
    const int qt = 15 - blockIdx.y;                // LPT: heavy diagonal blocks dispatch first
    const size_t base = (size_t)bh * 131072;
    const int wrow0 = qt * 128 + w * 32;

    // Q as B-operand fragments (same per-lane mapping as A): Q[q = nt*16+l15][d = ks*32+quad*8 ..]
    bf16x8 qf[2][2];
#pragma unroll
    for (int nt = 0; nt < 2; nt++)
#pragma unroll
        for (int ks = 0; ks < 2; ks++)
            qf[nt][ks] = *(const bf16x8*)(q + base + (size_t)(wrow0 + nt * 16 + l15) * 64 + ks * 32 + quad * 8);

    float m_[2], l_[2];                            // per q-column (this lane's l15 column)
    m_[0] = m_[1] = -1e30f;
    l_[0] = l_[1] = 0.f;
    f32x4 oacc[2][4] = {};

    const int ktmax = (qt + 1) * 2;
    const int srow = tid >> 3, sc8 = (tid & 7) * 8;

    for (int kt = 0; kt < ktmax; kt++) {
        __syncthreads();
#pragma unroll
        for (int ph = 0; ph < 2; ph++) {
            const int rr = srow + ph * 32;
            *(float4*)(Kt + rr * 72 + sc8) = *(const float4*)(k + base + (size_t)(kt * 64 + rr) * 64 + sc8);
            *(float4*)(Vt + rr * 72 + sc8) = *(const float4*)(vT + base + (size_t)rr * 2048 + kt * 64 + sc8);
        }
        __syncthreads();
        const bool act = (kt * 64 <= wrow0 + 31);
        if (act) {
            // S^T[k][q]: K rows as A, Q as B
            f32x4 st[4][2];
#pragma unroll
            for (int mt = 0; mt < 4; mt++) {
                bf16x8 kf0 = *(const bf16x8*)(Kt + (mt * 16 + l15) * 72 + quad * 8);
                bf16x8 kf1 = *(const bf16x8*)(Kt + (mt * 16 + l15) * 72 + 32 + quad * 8);
#pragma unroll
                for (int nt = 0; nt < 2; nt++) {
                    f32x4 z = {};
                    z = __builtin_amdgcn_mfma_f32_16x16x32_bf16(kf0, qf[nt][0], z, 0, 0, 0);
                    z = __builtin_amdgcn_mfma_f32_16x16x32_bf16(kf1, qf[nt][1], z, 0, 0, 0);
                    st[mt][nt] = z;
                }
            }
            const bool needmask = (kt * 64 + 63 > wrow0);  // wave-uniform: only diagonal tiles
            float alpha[2];
#pragma unroll
            for (int nt = 0; nt < 2; nt++) {
                const int qg = wrow0 + nt * 16 + l15;
                float mx = -1e30f;
                if (needmask) {
#pragma unroll
                    for (int mt = 0; mt < 4; mt++)
#pragma unroll
                        for (int r = 0; r < 4; r++) {
                            const int kg = kt * 64 + mt * 16 + quad * 4 + r;
                            float s = (kg <= qg) ? st[mt][nt][r] : -1e30f;
                            st[mt][nt][r] = s;
                            mx = fmaxf(mx, s);
                        }
                } else {
#pragma unroll
                    for (int mt = 0; mt < 4; mt++)
#pragma unroll
                        for (int r = 0; r < 4; r++) mx = fmaxf(mx, st[mt][nt][r]);
                }
                mx = fmaxf(mx, __shfl_xor(mx, 16, 64));
                mx = fmaxf(mx, __shfl_xor(mx, 32, 64));
                const float mnew = fmaxf(m_[nt], mx);
                alpha[nt] = exp2f(m_[nt] - mnew);
                m_[nt] = mnew;
                float rs = 0.f;
#pragma unroll
                for (int mt = 0; mt < 4; mt++) {
                    float p0 = exp2f(st[mt][nt][0] - mnew);
                    float p1 = exp2f(st[mt][nt][1] - mnew);
                    float p2 = exp2f(st[mt][nt][2] - mnew);
                    float p3 = exp2f(st[mt][nt][3] - mnew);
                    rs += (p0 + p1) + (p2 + p3);
                    bf16x4 pk = {(__bf16)p0, (__bf16)p1, (__bf16)p2, (__bf16)p3};
                    *(bf16x4*)(Pt[w] + (nt * 16 + l15) * 72 + mt * 16 + quad * 4) = pk;
                }
                rs += __shfl_xor(rs, 16, 64);
                rs += __shfl_xor(rs, 32, 64);
                l_[nt] = l_[nt] * alpha[nt] + rs;
            }
            // broadcast alpha from column-holder lanes (0..15) to row positions
            float arow[2][4];
#pragma unroll
            for (int mto = 0; mto < 2; mto++)
#pragma unroll
                for (int r = 0; r < 4; r++)
                    arow[mto][r] = __shfl(alpha[mto], quad * 4 + r, 64);
#pragma unroll
            for (int mto = 0; mto < 2; mto++)
#pragma unroll
                for (int ntv = 0; ntv < 4; ntv++)
#pragma unroll
                    for (int r = 0; r < 4; r++) oacc[mto][ntv][r] *= arow[mto][r];

            // PV: P as A-operand (from per-wave Pt), V^T as B-operand
            bf16x8 pf[2][2];
#pragma unroll
            for (int mto = 0; mto < 2; mto++)
#pragma unroll
                for (int ks = 0; ks < 2; ks++)
                    pf[mto][ks] = *(const bf16x8*)(Pt[w] + (mto * 16 + l15) * 72 + ks * 32 + quad * 8);
#pragma unroll
            for (int ntv = 0; ntv < 4; ntv++) {
                bf16x8 vf0 = *(const bf16x8*)(Vt + (ntv * 16 + l15) * 72 + quad * 8);
                bf16x8 vf1 = *(const bf16x8*)(Vt + (ntv * 16 + l15) * 72 + 32 + quad * 8);
#pragma unroll
                for (int mto = 0; mto < 2; mto++) {
                    oacc[mto][ntv] = __builtin_amdgcn_mfma_f32_16x16x32_bf16(pf[mto][0], vf0, oacc[mto][ntv], 0, 0, 0);
                    oacc[mto][ntv] = __builtin_amdgcn_mfma_f32_16x16x32_bf16(pf[mto][1], vf1, oacc[mto][ntv], 0, 0, 0);
                }
            }
        }
    }

    float linv[2] = {1.f / l_[0], 1.f / l_[1]};
    float rinv[2][4];
#pragma unroll
    for (int mto = 0; mto < 2; mto++)
#pragma unroll
        for (int r = 0; r < 4; r++)
            rinv[mto][r] = __shfl(linv[mto], quad * 4 + r, 64);

    const int b = bh >> 4, hh = bh & 15;
#pragma unroll
    for (int mto = 0; mto < 2; mto++)
#pragma unroll
        for (int ntv = 0; ntv < 4; ntv++)
#pragma unroll
            for (int r = 0; r < 4; r++) {
                const int trow = wrow0 + mto * 16 + quad * 4 + r;
                const int col = hh * 64 + ntv * 16 + l15;
                o[((size_t)b * 2048 + trow) * 1024 + col] = f2b(oacc[mto][ntv][r] * rinv[mto][r]);
            }
}

// ---------------------------------------------------------------- fused residual-add + layernorm
// ADD_BF16=1: add operand is bf16; else f32. g,b are f32.
template <int ADD_BF16>
__global__ __launch_bounds__(256) void ln_kernel(const float* __restrict__ hin,
                                                 const void* __restrict__ addp,
                                                 const float* __restrict__ g,
                                                 const float* __restrict__ bt,
                                                 float* __restrict__ hf_out,
                                                 u16* __restrict__ hb_out) {
    const int w = threadIdx.x >> 6, lane = threadIdx.x & 63;
    const size_t row = (size_t)blockIdx.x * 4 + w;
    const float4* hr = (const float4*)(hin + row * 1024);
    float4 xv[4];
    float s = 0.f, s2 = 0.f;
#pragma unroll
    for (int j = 0; j < 4; j++) {
        const int idx = lane + 64 * j;
        float4 a = hr[idx];
        float4 b;
        if (ADD_BF16) {
            ushort4 av = ((const ushort4*)addp)[row * 256 + idx];
            b.x = b2f(av.x); b.y = b2f(av.y); b.z = b2f(av.z); b.w = b2f(av.w);
        } else {
            b = ((const float4*)addp)[row * 256 + idx];
        }
        float4 x;
        x.x = a.x + b.x; x.y = a.y + b.y; x.z = a.z + b.z; x.w = a.w + b.w;
        xv[j] = x;
        s += x.x + x.y + x.z + x.w;
        s2 += x.x * x.x + x.y * x.y + x.z * x.z + x.w * x.w;
    }
#pragma unroll
    for (int mm = 1; mm < 64; mm <<= 1) { s += __shfl_xor(s, mm, 64); s2 += __shfl_xor(s2, mm, 64); }
    const float mean = s * (1.f / 1024.f);
    const float var = s2 * (1.f / 1024.f) - mean * mean;
    const float rstd = rsqrtf(var + 1e-5f);
    float4* of = (float4*)(hf_out + row * 1024);
    ushort4* ob = (ushort4*)(hb_out + row * 1024);
    const float4* gv = (const float4*)g;
    const float4* bv = (const float4*)bt;
#pragma unroll
    for (int j = 0; j < 4; j++) {
        const int idx = lane + 64 * j;
        float4 gg = gv[idx], bb = bv[idx];
        float4 x = xv[j], y;
        y.x = (x.x - mean) * rstd * gg.x + bb.x;
        y.y = (x.y - mean) * rstd * gg.y + bb.y;
        y.z = (x.z - mean) * rstd * gg.z + bb.z;
        y.w = (x.w - mean) * rstd * gg.w + bb.w;
        of[idx] = y;
        ushort4 oo;
        oo.x = f2b(y.x); oo.y = f2b(y.y); oo.z = f2b(y.z); oo.w = f2b(y.w);
        ob[idx] = oo;
    }
}

// ---------------------------------------------------------------- host
extern "C" void kernel_launch(void* const* d_in, const int* in_sizes, int n_in,
                              void* d_out, int out_size, void* d_ws, size_t ws_size,
                              hipStream_t stream) {
    const float* x   = (const float*)d_in[0];
    const float* pe  = (const float*)d_in[1];
    const float* wq  = (const float*)d_in[2];
    const float* wk  = (const float*)d_in[3];
    const float* wv  = (const float*)d_in[4];
    const float* l1g = (const float*)d_in[5];
    const float* l1b = (const float*)d_in[6];
    const float* w1  = (const float*)d_in[7];
    const float* b1  = (const float*)d_in[8];
    const float* w2  = (const float*)d_in[9];
    const float* b2  = (const float*)d_in[10];
    const float* l2g = (const float*)d_in[11];
    const float* l2b = (const float*)d_in[12];

    // 60 MB workspace, lifetime-aliased (stream order makes aliasing safe):
    char* ws = (char*)d_ws;
    float* hf   = (float*)(ws);                  // [ 0,16M) f32 residual stream
    u16* hb     = (u16*)(ws + 16777216);         // [16,24M) bf16 mirror of h
    u16* qb     = (u16*)(ws + 25165824);         // [24,32M) Q bf16 (pre-scaled)
    u16* kb     = (u16*)(ws + 33554432);         // [32,40M) K bf16
    u16* vb     = (u16*)(ws + 41943040);         // [40,48M) V bf16 natural [bh][t][d]
    u16* wqkvT  = (u16*)(ws + 50331648);         // [48,54M) qkv weightsT (dead after QKV gemm)
    u16* vbt    = (u16*)(ws + 50331648);         // [48,56M) V^T [bh][d][t] (aliases wqkvT)
    u16* ob     = (u16*)(ws + 41943040);         // [40,48M) attn out bf16 (aliases vb; vb dead after transpose_v)
    u16* wslot  = (u16*)(ws + 25165824);         // [24,28M) FFN weight slot (aliases qb, dead after attn)
    u16* ub     = (u16*)(ws + 29360128);         // [28,44M) ffn hidden half bf16 [4096,2048]
    float* mb   = (float*)(ws + 46137344);       // [44,60M) ffn out f32 accumulator

    add_pe_kernel<<<4096, 256, 0, stream>>>(x, pe, hf, hb);

    for (int l = 0; l < 8; l++) {
        // --- QKV ---
        transpose_qkv_kernel<<<dim3(16, 16, 3), 256, 0, stream>>>(
            wq + (size_t)l * 1048576, wk + (size_t)l * 1048576, wv + (size_t)l * 1048576, wqkvT);
        gemm_kernel<0, 4><<<dim3(24, 32), 256, 0, stream>>>(hb, wqkvT, nullptr, qb, kb, vb, 3072, 1024);
        transpose_v_kernel<<<dim3(32, 32), 256, 0, stream>>>(vb, vbt);
        // --- attention ---
        attn_kernel<<<dim3(32, 16), 256, 0, stream>>>(qb, kb, vbt, ob);
        ln_kernel<1><<<1024, 256, 0, stream>>>(hf, ob, l1g + l * 1024, l1b + l * 1024, hf, hb);
        // --- FFN in two halves through one 4MB weight slot ---
        for (int half = 0; half < 2; half++) {
            transpose_cast_kernel<<<dim3(32, 16), 256, 0, stream>>>(
                w1 + (size_t)l * 4194304 + half * 2048, wslot, 4096, 1024);
            gemm_kernel<1, 4><<<dim3(16, 32), 256, 0, stream>>>(
                hb, wslot, b1 + l * 4096 + half * 2048, ub, nullptr, nullptr, 2048, 1024);
            transpose_cast_kernel<<<dim3(16, 32), 256, 0, stream>>>(
                w2 + (size_t)l * 4194304 + (size_t)half * 2048 * 1024, wslot, 1024, 2048);
            if (half == 0)
                gemm_kernel<2, 2><<<dim3(8, 64), 256, 0, stream>>>(
                    ub, wslot, b2 + l * 1024, mb, nullptr, nullptr, 1024, 2048);
            else
                gemm_kernel<3, 2><<<dim3(8, 64), 256, 0, stream>>>(
                    ub, wslot, nullptr, mb, nullptr, nullptr, 1024, 2048);
        }
        const bool last = (l == 7);
        ln_kernel<0><<<1024, 256, 0, stream>>>(hf, mb, l2g + l * 1024, l2b + l * 1024,
                                               last ? (float*)d_out : hf, hb);
    }
}